// Round 1
// baseline (1706.705 us; speedup 1.0000x reference)
//
#include <hip/hip_runtime.h>
#include <math.h>

#define BATCH 4
#define CDIM 256
#define NPIX 4096
#define NPB (CDIM * NPIX)   // 1048576 elements per batch for LN
#define HEADS 4
#define DH 32
#define HID 128
#define OQKV 384
#define ATTN_SCALE 0.1767766952966369f  // 32^-0.5
#define LN_EPS 1e-5f

// ---------------- LayerNorm stats: partial sums ----------------
__global__ __launch_bounds__(256) void ln_reduce(const float* __restrict__ x,
                                                 float* __restrict__ part) {
  const int blk = blockIdx.x;       // 256 blocks: 64 per batch
  const int b = blk >> 6;
  const int slice = blk & 63;
  const float4* xp = (const float4*)(x + (size_t)b * NPB) + (size_t)slice * 4096;
  const int t = threadIdx.x;
  float s = 0.f, ss = 0.f;
#pragma unroll
  for (int k = 0; k < 16; ++k) {
    float4 v = xp[t + k * 256];
    s += v.x + v.y + v.z + v.w;
    ss += v.x * v.x + v.y * v.y + v.z * v.z + v.w * v.w;
  }
#pragma unroll
  for (int d = 1; d < 64; d <<= 1) {
    s += __shfl_xor(s, d);
    ss += __shfl_xor(ss, d);
  }
  __shared__ float red[8];
  const int wv = t >> 6;
  if ((t & 63) == 0) { red[wv * 2] = s; red[wv * 2 + 1] = ss; }
  __syncthreads();
  if (t == 0) {
    part[blk * 2]     = red[0] + red[2] + red[4] + red[6];
    part[blk * 2 + 1] = red[1] + red[3] + red[5] + red[7];
  }
}

// ---------------- finalize: mu, rstd per batch ----------------
__global__ void ln_finalize(const float* __restrict__ part, float* __restrict__ stats) {
  const int t = threadIdx.x;        // 256 threads, 1 block; wave b handles batch b
  const int b = t >> 6, lane = t & 63;
  float s  = part[(b * 64 + lane) * 2];
  float ss = part[(b * 64 + lane) * 2 + 1];
#pragma unroll
  for (int d = 1; d < 64; d <<= 1) {
    s += __shfl_xor(s, d);
    ss += __shfl_xor(ss, d);
  }
  if (lane == 0) {
    float mu = s * (1.f / (float)NPB);
    float var = ss * (1.f / (float)NPB) - mu * mu;
    stats[b * 2] = mu;
    stats[b * 2 + 1] = rsqrtf(var + LN_EPS);
  }
}

// ---------------- fused LN-normalize + QKV projection GEMM ----------------
// qkvb[b][o][p] = sum_c wqkv[o][c] * (x[b][c][p]*ga[c] + bb[c]),  o<384, p<4096
__global__ __launch_bounds__(256) void qkv_gemm(const float* __restrict__ x,
                                                const float* __restrict__ gamma,
                                                const float* __restrict__ beta,
                                                const float* __restrict__ wqkv,
                                                const float* __restrict__ stats,
                                                float* __restrict__ qkvb) {
  const int b = blockIdx.z;
  const int o0 = blockIdx.y * 64;
  const int p0 = blockIdx.x * 64;
  const int t = threadIdx.x;
  const float mu = stats[2 * b];
  const float rstd = stats[2 * b + 1];
  __shared__ float As[16][64];   // [k][o]
  __shared__ float Bs[16][68];   // [k][p], padded for banks + float4 alignment
  const int to = t >> 4;         // 0..15 (o quad)
  const int tp = t & 15;         // 0..15 (p quad)
  const int lo = t >> 2;         // A load row 0..63
  const int lkq = (t & 3) * 4;   // A load k quad
  const int lk = t >> 4;         // B load k row 0..15
  const int lpq = (t & 15) * 4;  // B load p quad
  float acc[4][4] = {};
  for (int k0 = 0; k0 < CDIM; k0 += 16) {
    float4 w4 = *(const float4*)(wqkv + (size_t)(o0 + lo) * CDIM + k0 + lkq);
    const int c = k0 + lk;
    const float ga = gamma[c] * rstd;
    const float bb = beta[c] - mu * ga;
    float4 v4 = *(const float4*)(x + ((size_t)b * CDIM + c) * NPIX + p0 + lpq);
    As[lkq + 0][lo] = w4.x; As[lkq + 1][lo] = w4.y;
    As[lkq + 2][lo] = w4.z; As[lkq + 3][lo] = w4.w;
    *(float4*)&Bs[lk][lpq] = make_float4(v4.x * ga + bb, v4.y * ga + bb,
                                         v4.z * ga + bb, v4.w * ga + bb);
    __syncthreads();
#pragma unroll
    for (int k = 0; k < 16; ++k) {
      float4 a4 = *(const float4*)&As[k][to * 4];
      float4 b4 = *(const float4*)&Bs[k][tp * 4];
      acc[0][0] += a4.x * b4.x; acc[0][1] += a4.x * b4.y; acc[0][2] += a4.x * b4.z; acc[0][3] += a4.x * b4.w;
      acc[1][0] += a4.y * b4.x; acc[1][1] += a4.y * b4.y; acc[1][2] += a4.y * b4.z; acc[1][3] += a4.y * b4.w;
      acc[2][0] += a4.z * b4.x; acc[2][1] += a4.z * b4.y; acc[2][2] += a4.z * b4.z; acc[2][3] += a4.z * b4.w;
      acc[3][0] += a4.w * b4.x; acc[3][1] += a4.w * b4.y; acc[3][2] += a4.w * b4.z; acc[3][3] += a4.w * b4.w;
    }
    __syncthreads();
  }
#pragma unroll
  for (int i = 0; i < 4; ++i) {
    *(float4*)(qkvb + ((size_t)b * OQKV + o0 + to * 4 + i) * NPIX + p0 + tp * 4) =
        make_float4(acc[i][0], acc[i][1], acc[i][2], acc[i][3]);
  }
}

// ---------------- flash attention, fp32 ----------------
// per block: one (b,h) and a 64-row query tile; loop over 64-col K/V tiles
__global__ __launch_bounds__(256) void attn_kernel(const float* __restrict__ qkvb,
                                                   float* __restrict__ obuf) {
  const int i0 = blockIdx.x * 64;
  const int h = blockIdx.y;
  const int b = blockIdx.z;
  const int t = threadIdx.x;
  const int i4 = t >> 4;   // 0..15 row group (4 rows each)
  const int j4 = t & 15;   // 0..15 col group (4 cols each)

  __shared__ float Qs[32][64];
  __shared__ float Ks[32][64];
  __shared__ float Vs[32][65];   // +1 pad: PV does strided b32 reads
  __shared__ float Os[32][64];

  const float* qbase = qkvb + ((size_t)b * OQKV + h * DH) * NPIX;
  const float* kbase = qkvb + ((size_t)b * OQKV + HID + h * DH) * NPIX;
  const float* vbase = qkvb + ((size_t)b * OQKV + 2 * HID + h * DH) * NPIX;

  for (int idx = t; idx < 32 * 64; idx += 256) {
    int c = idx >> 6, col = idx & 63;
    Qs[c][col] = qbase[(size_t)c * NPIX + i0 + col] * ATTN_SCALE;
  }

  float O[4][32];
#pragma unroll
  for (int r = 0; r < 4; ++r)
#pragma unroll
    for (int c = 0; c < 32; ++c) O[r][c] = 0.f;
  float m[4] = {-1e30f, -1e30f, -1e30f, -1e30f};
  float l[4] = {0.f, 0.f, 0.f, 0.f};

  for (int jt = 0; jt < NPIX; jt += 64) {
    __syncthreads();   // previous tile's reads done (also covers Qs first use)
    for (int idx = t; idx < 32 * 64; idx += 256) {
      int c = idx >> 6, col = idx & 63;
      Ks[c][col] = kbase[(size_t)c * NPIX + jt + col];
      Vs[c][col] = vbase[(size_t)c * NPIX + jt + col];
    }
    __syncthreads();

    // S = Q^T K  (4x4 per thread)
    float s[4][4] = {};
#pragma unroll
    for (int c = 0; c < 32; ++c) {
      float4 qv = *(const float4*)&Qs[c][i4 * 4];
      float4 kv = *(const float4*)&Ks[c][j4 * 4];
      s[0][0] += qv.x * kv.x; s[0][1] += qv.x * kv.y; s[0][2] += qv.x * kv.z; s[0][3] += qv.x * kv.w;
      s[1][0] += qv.y * kv.x; s[1][1] += qv.y * kv.y; s[1][2] += qv.y * kv.z; s[1][3] += qv.y * kv.w;
      s[2][0] += qv.z * kv.x; s[2][1] += qv.z * kv.y; s[2][2] += qv.z * kv.z; s[2][3] += qv.z * kv.w;
      s[3][0] += qv.w * kv.x; s[3][1] += qv.w * kv.y; s[3][2] += qv.w * kv.z; s[3][3] += qv.w * kv.w;
    }

    // online softmax per row (reduce across the 16 j4 lanes, same wave)
#pragma unroll
    for (int r = 0; r < 4; ++r) {
      float mx = fmaxf(fmaxf(s[r][0], s[r][1]), fmaxf(s[r][2], s[r][3]));
#pragma unroll
      for (int d = 1; d < 16; d <<= 1) mx = fmaxf(mx, __shfl_xor(mx, d));
      const float mnew = fmaxf(m[r], mx);
      s[r][0] = __expf(s[r][0] - mnew);
      s[r][1] = __expf(s[r][1] - mnew);
      s[r][2] = __expf(s[r][2] - mnew);
      s[r][3] = __expf(s[r][3] - mnew);
      float ls = s[r][0] + s[r][1] + s[r][2] + s[r][3];
#pragma unroll
      for (int d = 1; d < 16; d <<= 1) ls += __shfl_xor(ls, d);
      const float alpha = __expf(m[r] - mnew);
      l[r] = l[r] * alpha + ls;
      if (alpha != 1.f) {
#pragma unroll
        for (int c = 0; c < 32; ++c) O[r][c] *= alpha;
      }
      m[r] = mnew;
    }

    // O += P V^T over this thread's 4 j columns
#pragma unroll
    for (int jj = 0; jj < 4; ++jj) {
      const int j = j4 * 4 + jj;
      const float p0 = s[0][jj], p1 = s[1][jj], p2 = s[2][jj], p3 = s[3][jj];
#pragma unroll
      for (int c = 0; c < 32; ++c) {
        const float v = Vs[c][j];
        O[0][c] += p0 * v; O[1][c] += p1 * v; O[2][c] += p2 * v; O[3][c] += p3 * v;
      }
    }
  }

  // reduce O partials across the 16 j4 lanes
#pragma unroll
  for (int r = 0; r < 4; ++r)
#pragma unroll
    for (int c = 0; c < 32; ++c) {
#pragma unroll
      for (int d = 1; d < 16; d <<= 1) O[r][c] += __shfl_xor(O[r][c], d);
    }

  if (j4 == 0) {
#pragma unroll
    for (int r = 0; r < 4; ++r) {
      const float invl = 1.f / l[r];
#pragma unroll
      for (int c = 0; c < 32; ++c) Os[c][i4 * 4 + r] = O[r][c] * invl;
    }
  }
  __syncthreads();
  for (int idx = t; idx < 32 * 64; idx += 256) {
    int c = idx >> 6, col = idx & 63;
    obuf[((size_t)b * HID + h * DH + c) * NPIX + i0 + col] = Os[c][col];
  }
}

// ---------------- output projection GEMM + bias ----------------
// y[b][o][p] = bout[o] + sum_{c<128} wout[o][c] * obuf[b][c][p]
__global__ __launch_bounds__(256) void out_gemm(const float* __restrict__ obuf,
                                                const float* __restrict__ wout,
                                                const float* __restrict__ bout,
                                                float* __restrict__ y) {
  const int b = blockIdx.z;
  const int o0 = blockIdx.y * 64;
  const int p0 = blockIdx.x * 64;
  const int t = threadIdx.x;
  __shared__ float As[16][64];
  __shared__ float Bs[16][68];
  const int to = t >> 4;
  const int tp = t & 15;
  const int lo = t >> 2;
  const int lkq = (t & 3) * 4;
  const int lk = t >> 4;
  const int lpq = (t & 15) * 4;
  float acc[4][4] = {};
  for (int k0 = 0; k0 < HID; k0 += 16) {
    float4 w4 = *(const float4*)(wout + (size_t)(o0 + lo) * HID + k0 + lkq);
    float4 v4 = *(const float4*)(obuf + ((size_t)b * HID + k0 + lk) * NPIX + p0 + lpq);
    As[lkq + 0][lo] = w4.x; As[lkq + 1][lo] = w4.y;
    As[lkq + 2][lo] = w4.z; As[lkq + 3][lo] = w4.w;
    *(float4*)&Bs[lk][lpq] = v4;
    __syncthreads();
#pragma unroll
    for (int k = 0; k < 16; ++k) {
      float4 a4 = *(const float4*)&As[k][to * 4];
      float4 b4 = *(const float4*)&Bs[k][tp * 4];
      acc[0][0] += a4.x * b4.x; acc[0][1] += a4.x * b4.y; acc[0][2] += a4.x * b4.z; acc[0][3] += a4.x * b4.w;
      acc[1][0] += a4.y * b4.x; acc[1][1] += a4.y * b4.y; acc[1][2] += a4.y * b4.z; acc[1][3] += a4.y * b4.w;
      acc[2][0] += a4.z * b4.x; acc[2][1] += a4.z * b4.y; acc[2][2] += a4.z * b4.z; acc[2][3] += a4.z * b4.w;
      acc[3][0] += a4.w * b4.x; acc[3][1] += a4.w * b4.y; acc[3][2] += a4.w * b4.z; acc[3][3] += a4.w * b4.w;
    }
    __syncthreads();
  }
#pragma unroll
  for (int i = 0; i < 4; ++i) {
    const float bias = bout[o0 + to * 4 + i];
    *(float4*)(y + ((size_t)b * CDIM + o0 + to * 4 + i) * NPIX + p0 + tp * 4) =
        make_float4(acc[i][0] + bias, acc[i][1] + bias, acc[i][2] + bias, acc[i][3] + bias);
  }
}

extern "C" void kernel_launch(void* const* d_in, const int* in_sizes, int n_in,
                              void* d_out, int out_size, void* d_ws, size_t ws_size,
                              hipStream_t stream) {
  const float* x     = (const float*)d_in[0];
  const float* gamma = (const float*)d_in[1];
  const float* beta  = (const float*)d_in[2];
  const float* wqkv  = (const float*)d_in[3];
  const float* wout  = (const float*)d_in[4];
  const float* bout  = (const float*)d_in[5];
  float* y = (float*)d_out;

  float* ws    = (float*)d_ws;
  float* part  = ws;                 // 512 floats
  float* stats = ws + 512;           // 8 floats (mu, rstd per batch)
  float* qkvb  = ws + 1024;          // 4*384*4096 = 6291456 floats
  float* obuf  = qkvb + (size_t)BATCH * OQKV * NPIX;  // 4*128*4096 = 2097152 floats

  ln_reduce<<<dim3(256), 256, 0, stream>>>(x, part);
  ln_finalize<<<dim3(1), 256, 0, stream>>>(part, stats);
  qkv_gemm<<<dim3(64, 6, BATCH), 256, 0, stream>>>(x, gamma, beta, wqkv, stats, qkvb);
  attn_kernel<<<dim3(64, HEADS, BATCH), 256, 0, stream>>>(qkvb, obuf);
  out_gemm<<<dim3(64, 4, BATCH), 256, 0, stream>>>(obuf, wout, bout, y);
}

// Round 2
// 329.845 us; speedup vs baseline: 5.1743x; 5.1743x over previous
//
#include <hip/hip_runtime.h>
#include <math.h>

#define BATCH 4
#define CDIM 256
#define NPIX 4096
#define NPB (CDIM * NPIX)
#define HEADS 4
#define DH 32
#define HID 128
#define OQKV 384
#define ATTN_SCALE 0.1767766952966369f  // 32^-0.5
#define LN_EPS 1e-5f

typedef _Float16 f16;
typedef _Float16 f16x8 __attribute__((ext_vector_type(8)));
typedef _Float16 f16x4 __attribute__((ext_vector_type(4)));
typedef float f32x4 __attribute__((ext_vector_type(4)));

// ---------------- LayerNorm stats: partial sums ----------------
__global__ __launch_bounds__(256) void ln_reduce(const float* __restrict__ x,
                                                 float* __restrict__ part) {
  const int blk = blockIdx.x;
  const int b = blk >> 6;
  const int slice = blk & 63;
  const float4* xp = (const float4*)(x + (size_t)b * NPB) + (size_t)slice * 4096;
  const int t = threadIdx.x;
  float s = 0.f, ss = 0.f;
#pragma unroll
  for (int k = 0; k < 16; ++k) {
    float4 v = xp[t + k * 256];
    s += v.x + v.y + v.z + v.w;
    ss += v.x * v.x + v.y * v.y + v.z * v.z + v.w * v.w;
  }
#pragma unroll
  for (int d = 1; d < 64; d <<= 1) {
    s += __shfl_xor(s, d);
    ss += __shfl_xor(ss, d);
  }
  __shared__ float red[8];
  const int wv = t >> 6;
  if ((t & 63) == 0) { red[wv * 2] = s; red[wv * 2 + 1] = ss; }
  __syncthreads();
  if (t == 0) {
    part[blk * 2]     = red[0] + red[2] + red[4] + red[6];
    part[blk * 2 + 1] = red[1] + red[3] + red[5] + red[7];
  }
}

__global__ void ln_finalize(const float* __restrict__ part, float* __restrict__ stats) {
  const int t = threadIdx.x;
  const int b = t >> 6, lane = t & 63;
  float s  = part[(b * 64 + lane) * 2];
  float ss = part[(b * 64 + lane) * 2 + 1];
#pragma unroll
  for (int d = 1; d < 64; d <<= 1) {
    s += __shfl_xor(s, d);
    ss += __shfl_xor(ss, d);
  }
  if (lane == 0) {
    float mu = s * (1.f / (float)NPB);
    float var = ss * (1.f / (float)NPB) - mu * mu;
    stats[b * 2] = mu;
    stats[b * 2 + 1] = rsqrtf(var + LN_EPS);
  }
}

// ---------------- fused LN-normalize + QKV projection GEMM ----------------
// Emits: qT[b][h][p][c] f16 (pre-scaled), kT[b][h][p][c] f16, vO[b][h][c][p] f16
__global__ __launch_bounds__(256) void qkv_gemm(const float* __restrict__ x,
                                                const float* __restrict__ gamma,
                                                const float* __restrict__ beta,
                                                const float* __restrict__ wqkv,
                                                const float* __restrict__ stats,
                                                f16* __restrict__ qT,
                                                f16* __restrict__ kT,
                                                f16* __restrict__ vO) {
  const int b = blockIdx.z;
  const int o0 = blockIdx.y * 64;
  const int p0 = blockIdx.x * 64;
  const int t = threadIdx.x;
  const float mu = stats[2 * b];
  const float rstd = stats[2 * b + 1];
  __shared__ float As[16][64];
  __shared__ float Bs[16][68];
  const int to = t >> 4;
  const int tp = t & 15;
  const int lo = t >> 2;
  const int lkq = (t & 3) * 4;
  const int lk = t >> 4;
  const int lpq = (t & 15) * 4;
  float acc[4][4] = {};
  for (int k0 = 0; k0 < CDIM; k0 += 16) {
    float4 w4 = *(const float4*)(wqkv + (size_t)(o0 + lo) * CDIM + k0 + lkq);
    const int c = k0 + lk;
    const float ga = gamma[c] * rstd;
    const float bb = beta[c] - mu * ga;
    float4 v4 = *(const float4*)(x + ((size_t)b * CDIM + c) * NPIX + p0 + lpq);
    As[lkq + 0][lo] = w4.x; As[lkq + 1][lo] = w4.y;
    As[lkq + 2][lo] = w4.z; As[lkq + 3][lo] = w4.w;
    *(float4*)&Bs[lk][lpq] = make_float4(v4.x * ga + bb, v4.y * ga + bb,
                                         v4.z * ga + bb, v4.w * ga + bb);
    __syncthreads();
#pragma unroll
    for (int k = 0; k < 16; ++k) {
      float4 a4 = *(const float4*)&As[k][to * 4];
      float4 b4 = *(const float4*)&Bs[k][tp * 4];
      acc[0][0] += a4.x * b4.x; acc[0][1] += a4.x * b4.y; acc[0][2] += a4.x * b4.z; acc[0][3] += a4.x * b4.w;
      acc[1][0] += a4.y * b4.x; acc[1][1] += a4.y * b4.y; acc[1][2] += a4.y * b4.z; acc[1][3] += a4.y * b4.w;
      acc[2][0] += a4.z * b4.x; acc[2][1] += a4.z * b4.y; acc[2][2] += a4.z * b4.z; acc[2][3] += a4.z * b4.w;
      acc[3][0] += a4.w * b4.x; acc[3][1] += a4.w * b4.y; acc[3][2] += a4.w * b4.z; acc[3][3] += a4.w * b4.w;
    }
    __syncthreads();
  }
  const int o_base = o0 + to * 4;   // multiple of 4; all 4 rows share a head
  const int p_base = p0 + tp * 4;
  if (o_base < HID) {               // ---- Q: qT[b][h][p][c], pre-scaled
    const int h = o_base >> 5, c0 = o_base & 31;
    f16* base = qT + ((size_t)(b * HEADS + h) * NPIX) * DH + c0;
#pragma unroll
    for (int j = 0; j < 4; ++j) {
      f16x4 v = {(f16)(acc[0][j] * ATTN_SCALE), (f16)(acc[1][j] * ATTN_SCALE),
                 (f16)(acc[2][j] * ATTN_SCALE), (f16)(acc[3][j] * ATTN_SCALE)};
      *(f16x4*)(base + (size_t)(p_base + j) * DH) = v;
    }
  } else if (o_base < 2 * HID) {    // ---- K: kT[b][h][p][c]
    const int och = o_base - HID;
    const int h = och >> 5, c0 = och & 31;
    f16* base = kT + ((size_t)(b * HEADS + h) * NPIX) * DH + c0;
#pragma unroll
    for (int j = 0; j < 4; ++j) {
      f16x4 v = {(f16)acc[0][j], (f16)acc[1][j], (f16)acc[2][j], (f16)acc[3][j]};
      *(f16x4*)(base + (size_t)(p_base + j) * DH) = v;
    }
  } else {                          // ---- V: vO[b][h][c][p]
    const int och = o_base - 2 * HID;
    const int h = och >> 5, c0 = och & 31;
#pragma unroll
    for (int i = 0; i < 4; ++i) {
      f16x4 v = {(f16)acc[i][0], (f16)acc[i][1], (f16)acc[i][2], (f16)acc[i][3]};
      *(f16x4*)(vO + ((size_t)(b * HEADS + h) * DH + c0 + i) * NPIX + p_base) = v;
    }
  }
}

// ---------------- flash attention, f16 MFMA ----------------
// block: one (b,h), 64 query rows; 4 waves x 16 rows; 64-wide K/V tiles.
// MFMA 16x16x32: A[m=lane&15][k=quad*8+j], B[n=lane&15][k=quad*8+j],
//                C/D row=quad*4+reg, col=lane&15  (m120-verified layouts)
__global__ __launch_bounds__(256, 2) void attn_kernel(const f16* __restrict__ qT,
                                                      const f16* __restrict__ kT,
                                                      const f16* __restrict__ vO,
                                                      float* __restrict__ obuf) {
  const int i0 = blockIdx.x * 64;
  const int h = blockIdx.y;
  const int b = blockIdx.z;
  const int t = threadIdx.x;
  const int w = t >> 6;
  const int lane = t & 63;
  const int low4 = lane & 15;
  const int quad = lane >> 4;

  __shared__ f16 Kt_s[64][40];      // [j][c], row stride 80B (16B-mult)
  __shared__ f16 V_s[32][72];       // [c][j], row stride 144B
  __shared__ f16 P_s[4][16][72];    // wave-private [i][j]
  __shared__ float Os[32][65];      // [c][i] epilogue transpose

  const size_t bh = (size_t)(b * HEADS + h);
  const f16* kTb = kT + bh * NPIX * DH;
  const f16* vb_ = vO + bh * DH * NPIX;

  // Q fragment (A-layout), pre-scaled in qkv_gemm
  f16x8 qf = *(const f16x8*)(qT + (bh * NPIX + i0 + w * 16 + low4) * DH + quad * 8);

  f32x4 ov0 = {0.f, 0.f, 0.f, 0.f}, ov1 = {0.f, 0.f, 0.f, 0.f};
  float mr[4] = {-1e30f, -1e30f, -1e30f, -1e30f};
  float lr[4] = {0.f, 0.f, 0.f, 0.f};
  const f32x4 zero = {0.f, 0.f, 0.f, 0.f};

  for (int jt = 0; jt < NPIX; jt += 64) {
    __syncthreads();   // prior tile's frag reads complete
    // stage K-tile [64j][32c] (contiguous 4KB) and V-tile [32c][64j]
    *(f16x8*)&Kt_s[t >> 2][(t & 3) * 8] =
        *(const f16x8*)(kTb + (size_t)(jt + (t >> 2)) * DH + (t & 3) * 8);
    *(f16x8*)&V_s[t >> 3][(t & 7) * 8] =
        *(const f16x8*)(vb_ + (size_t)(t >> 3) * NPIX + jt + (t & 7) * 8);
    __syncthreads();

    // S = Q K^T : 4 MFMAs cover 16 rows x 64 cols (K-dim = DH = 32, complete)
    f16x8 kb[4];
    f32x4 st[4];
#pragma unroll
    for (int tt = 0; tt < 4; ++tt)
      kb[tt] = *(const f16x8*)&Kt_s[16 * tt + low4][quad * 8];
#pragma unroll
    for (int tt = 0; tt < 4; ++tt)
      st[tt] = __builtin_amdgcn_mfma_f32_16x16x32_f16(qf, kb[tt], zero, 0, 0, 0);

    // online softmax; lane holds rows i=quad*4+r, cols 16*tt+low4
#pragma unroll
    for (int r = 0; r < 4; ++r) {
      float mx = fmaxf(fmaxf(st[0][r], st[1][r]), fmaxf(st[2][r], st[3][r]));
      mx = fmaxf(mx, __shfl_xor(mx, 1));
      mx = fmaxf(mx, __shfl_xor(mx, 2));
      mx = fmaxf(mx, __shfl_xor(mx, 4));
      mx = fmaxf(mx, __shfl_xor(mx, 8));
      const float mn = fmaxf(mr[r], mx);
      const float al = __expf(mr[r] - mn);
      mr[r] = mn;
      const float e0 = __expf(st[0][r] - mn);
      const float e1 = __expf(st[1][r] - mn);
      const float e2 = __expf(st[2][r] - mn);
      const float e3 = __expf(st[3][r] - mn);
      float sm = e0 + e1 + e2 + e3;
      sm += __shfl_xor(sm, 1);
      sm += __shfl_xor(sm, 2);
      sm += __shfl_xor(sm, 4);
      sm += __shfl_xor(sm, 8);
      lr[r] = lr[r] * al + sm;
      ov0[r] *= al; ov1[r] *= al;
      // P -> LDS (C-layout scatter; read back below in A-layout)
      P_s[w][quad * 4 + r][low4]      = (f16)e0;
      P_s[w][quad * 4 + r][16 + low4] = (f16)e1;
      P_s[w][quad * 4 + r][32 + low4] = (f16)e2;
      P_s[w][quad * 4 + r][48 + low4] = (f16)e3;
    }

    // O += P V^T : A = P (16i x 64j), B = V (j x c), 2 c-tiles x 2 j-steps
    f16x8 pa0 = *(const f16x8*)&P_s[w][low4][quad * 8];
    f16x8 pa1 = *(const f16x8*)&P_s[w][low4][32 + quad * 8];
    f16x8 va00 = *(const f16x8*)&V_s[low4][quad * 8];
    f16x8 va01 = *(const f16x8*)&V_s[low4][32 + quad * 8];
    f16x8 va10 = *(const f16x8*)&V_s[16 + low4][quad * 8];
    f16x8 va11 = *(const f16x8*)&V_s[16 + low4][32 + quad * 8];
    ov0 = __builtin_amdgcn_mfma_f32_16x16x32_f16(pa0, va00, ov0, 0, 0, 0);
    ov0 = __builtin_amdgcn_mfma_f32_16x16x32_f16(pa1, va01, ov0, 0, 0, 0);
    ov1 = __builtin_amdgcn_mfma_f32_16x16x32_f16(pa0, va10, ov1, 0, 0, 0);
    ov1 = __builtin_amdgcn_mfma_f32_16x16x32_f16(pa1, va11, ov1, 0, 0, 0);
  }

  // epilogue: normalize, transpose via LDS, coalesced store
#pragma unroll
  for (int r = 0; r < 4; ++r) {
    const float inv = 1.f / lr[r];
    Os[low4][w * 16 + quad * 4 + r]      = ov0[r] * inv;
    Os[16 + low4][w * 16 + quad * 4 + r] = ov1[r] * inv;
  }
  __syncthreads();
  float* ob = obuf + ((size_t)b * HID + h * DH) * NPIX;
  for (int idx = t; idx < DH * 64; idx += 256) {
    int c = idx >> 6, col = idx & 63;
    ob[(size_t)c * NPIX + i0 + col] = Os[c][col];
  }
}

// ---------------- output projection GEMM + bias ----------------
__global__ __launch_bounds__(256) void out_gemm(const float* __restrict__ obuf,
                                                const float* __restrict__ wout,
                                                const float* __restrict__ bout,
                                                float* __restrict__ y) {
  const int b = blockIdx.z;
  const int o0 = blockIdx.y * 64;
  const int p0 = blockIdx.x * 64;
  const int t = threadIdx.x;
  __shared__ float As[16][64];
  __shared__ float Bs[16][68];
  const int to = t >> 4;
  const int tp = t & 15;
  const int lo = t >> 2;
  const int lkq = (t & 3) * 4;
  const int lk = t >> 4;
  const int lpq = (t & 15) * 4;
  float acc[4][4] = {};
  for (int k0 = 0; k0 < HID; k0 += 16) {
    float4 w4 = *(const float4*)(wout + (size_t)(o0 + lo) * HID + k0 + lkq);
    float4 v4 = *(const float4*)(obuf + ((size_t)b * HID + k0 + lk) * NPIX + p0 + lpq);
    As[lkq + 0][lo] = w4.x; As[lkq + 1][lo] = w4.y;
    As[lkq + 2][lo] = w4.z; As[lkq + 3][lo] = w4.w;
    *(float4*)&Bs[lk][lpq] = v4;
    __syncthreads();
#pragma unroll
    for (int k = 0; k < 16; ++k) {
      float4 a4 = *(const float4*)&As[k][to * 4];
      float4 b4 = *(const float4*)&Bs[k][tp * 4];
      acc[0][0] += a4.x * b4.x; acc[0][1] += a4.x * b4.y; acc[0][2] += a4.x * b4.z; acc[0][3] += a4.x * b4.w;
      acc[1][0] += a4.y * b4.x; acc[1][1] += a4.y * b4.y; acc[1][2] += a4.y * b4.z; acc[1][3] += a4.y * b4.w;
      acc[2][0] += a4.z * b4.x; acc[2][1] += a4.z * b4.y; acc[2][2] += a4.z * b4.z; acc[2][3] += a4.z * b4.w;
      acc[3][0] += a4.w * b4.x; acc[3][1] += a4.w * b4.y; acc[3][2] += a4.w * b4.z; acc[3][3] += a4.w * b4.w;
    }
    __syncthreads();
  }
#pragma unroll
  for (int i = 0; i < 4; ++i) {
    const float bias = bout[o0 + to * 4 + i];
    *(float4*)(y + ((size_t)b * CDIM + o0 + to * 4 + i) * NPIX + p0 + tp * 4) =
        make_float4(acc[i][0] + bias, acc[i][1] + bias, acc[i][2] + bias, acc[i][3] + bias);
  }
}

extern "C" void kernel_launch(void* const* d_in, const int* in_sizes, int n_in,
                              void* d_out, int out_size, void* d_ws, size_t ws_size,
                              hipStream_t stream) {
  const float* x     = (const float*)d_in[0];
  const float* gamma = (const float*)d_in[1];
  const float* beta  = (const float*)d_in[2];
  const float* wqkv  = (const float*)d_in[3];
  const float* wout  = (const float*)d_in[4];
  const float* bout  = (const float*)d_in[5];
  float* y = (float*)d_out;

  char* wsb = (char*)d_ws;
  float* part  = (float*)wsb;                       // 512 floats
  float* stats = part + 512;                        // 8 floats
  f16* qT = (f16*)(wsb + 4096);                     // 4*4*4096*32 f16 = 4MB
  f16* kT = qT + (size_t)BATCH * HEADS * NPIX * DH; // 4MB
  f16* vO = kT + (size_t)BATCH * HEADS * NPIX * DH; // 4MB
  float* obuf = (float*)(vO + (size_t)BATCH * HEADS * NPIX * DH);  // 8MB

  ln_reduce<<<dim3(256), 256, 0, stream>>>(x, part);
  ln_finalize<<<dim3(1), 256, 0, stream>>>(part, stats);
  qkv_gemm<<<dim3(64, 6, BATCH), 256, 0, stream>>>(x, gamma, beta, wqkv, stats, qT, kT, vO);
  attn_kernel<<<dim3(64, HEADS, BATCH), 256, 0, stream>>>(qT, kT, vO, obuf);
  out_gemm<<<dim3(64, 4, BATCH), 256, 0, stream>>>(obuf, wout, bout, y);
}

// Round 4
// 309.296 us; speedup vs baseline: 5.5180x; 1.0664x over previous
//
#include <hip/hip_runtime.h>
#include <math.h>

#define BATCH 4
#define CDIM 256
#define NPIX 4096
#define NPB (CDIM * NPIX)
#define HEADS 4
#define DH 32
#define HID 128
#define OQKV 384
#define ATTN_SCALE 0.1767766952966369f  // 32^-0.5
#define QK_SCALE (0.1767766952966369f * 1.44269504088896340736f)  // fold log2(e): softmax via exp2
#define LN_EPS 1e-5f

typedef _Float16 f16;
typedef _Float16 f16x8 __attribute__((ext_vector_type(8)));
typedef _Float16 f16x4 __attribute__((ext_vector_type(4)));
typedef float f32x4 __attribute__((ext_vector_type(4)));

// ---------------- LayerNorm stats: partial sums ----------------
__global__ __launch_bounds__(256) void ln_reduce(const float* __restrict__ x,
                                                 float* __restrict__ part) {
  const int blk = blockIdx.x;
  const int b = blk >> 6;
  const int slice = blk & 63;
  const float4* xp = (const float4*)(x + (size_t)b * NPB) + (size_t)slice * 4096;
  const int t = threadIdx.x;
  float s = 0.f, ss = 0.f;
#pragma unroll
  for (int k = 0; k < 16; ++k) {
    float4 v = xp[t + k * 256];
    s += v.x + v.y + v.z + v.w;
    ss += v.x * v.x + v.y * v.y + v.z * v.z + v.w * v.w;
  }
#pragma unroll
  for (int d = 1; d < 64; d <<= 1) {
    s += __shfl_xor(s, d);
    ss += __shfl_xor(ss, d);
  }
  __shared__ float red[8];
  const int wv = t >> 6;
  if ((t & 63) == 0) { red[wv * 2] = s; red[wv * 2 + 1] = ss; }
  __syncthreads();
  if (t == 0) {
    part[blk * 2]     = red[0] + red[2] + red[4] + red[6];
    part[blk * 2 + 1] = red[1] + red[3] + red[5] + red[7];
  }
}

__global__ void ln_finalize(const float* __restrict__ part, float* __restrict__ stats) {
  const int t = threadIdx.x;
  const int b = t >> 6, lane = t & 63;
  float s  = part[(b * 64 + lane) * 2];
  float ss = part[(b * 64 + lane) * 2 + 1];
#pragma unroll
  for (int d = 1; d < 64; d <<= 1) {
    s += __shfl_xor(s, d);
    ss += __shfl_xor(ss, d);
  }
  if (lane == 0) {
    float mu = s * (1.f / (float)NPB);
    float var = ss * (1.f / (float)NPB) - mu * mu;
    stats[b * 2] = mu;
    stats[b * 2 + 1] = rsqrtf(var + LN_EPS);
  }
}

// ---------------- fused LN-normalize + QKV projection GEMM ----------------
// Emits: qT[b][h][p][c] f16 (pre-scaled by QK_SCALE), kT[b][h][p][c] f16, vO[b][h][c][p] f16
__global__ __launch_bounds__(256) void qkv_gemm(const float* __restrict__ x,
                                                const float* __restrict__ gamma,
                                                const float* __restrict__ beta,
                                                const float* __restrict__ wqkv,
                                                const float* __restrict__ stats,
                                                f16* __restrict__ qT,
                                                f16* __restrict__ kT,
                                                f16* __restrict__ vO) {
  const int b = blockIdx.z;
  const int o0 = blockIdx.y * 64;
  const int p0 = blockIdx.x * 64;
  const int t = threadIdx.x;
  const float mu = stats[2 * b];
  const float rstd = stats[2 * b + 1];
  __shared__ float As[16][64];
  __shared__ float Bs[16][68];
  const int to = t >> 4;
  const int tp = t & 15;
  const int lo = t >> 2;
  const int lkq = (t & 3) * 4;
  const int lk = t >> 4;
  const int lpq = (t & 15) * 4;
  float acc[4][4] = {};
  for (int k0 = 0; k0 < CDIM; k0 += 16) {
    float4 w4 = *(const float4*)(wqkv + (size_t)(o0 + lo) * CDIM + k0 + lkq);
    const int c = k0 + lk;
    const float ga = gamma[c] * rstd;
    const float bb = beta[c] - mu * ga;
    float4 v4 = *(const float4*)(x + ((size_t)b * CDIM + c) * NPIX + p0 + lpq);
    As[lkq + 0][lo] = w4.x; As[lkq + 1][lo] = w4.y;
    As[lkq + 2][lo] = w4.z; As[lkq + 3][lo] = w4.w;
    *(float4*)&Bs[lk][lpq] = make_float4(v4.x * ga + bb, v4.y * ga + bb,
                                         v4.z * ga + bb, v4.w * ga + bb);
    __syncthreads();
#pragma unroll
    for (int k = 0; k < 16; ++k) {
      float4 a4 = *(const float4*)&As[k][to * 4];
      float4 b4 = *(const float4*)&Bs[k][tp * 4];
      acc[0][0] += a4.x * b4.x; acc[0][1] += a4.x * b4.y; acc[0][2] += a4.x * b4.z; acc[0][3] += a4.x * b4.w;
      acc[1][0] += a4.y * b4.x; acc[1][1] += a4.y * b4.y; acc[1][2] += a4.y * b4.z; acc[1][3] += a4.y * b4.w;
      acc[2][0] += a4.z * b4.x; acc[2][1] += a4.z * b4.y; acc[2][2] += a4.z * b4.z; acc[2][3] += a4.z * b4.w;
      acc[3][0] += a4.w * b4.x; acc[3][1] += a4.w * b4.y; acc[3][2] += a4.w * b4.z; acc[3][3] += a4.w * b4.w;
    }
    __syncthreads();
  }
  const int o_base = o0 + to * 4;
  const int p_base = p0 + tp * 4;
  if (o_base < HID) {               // ---- Q: qT[b][h][p][c], pre-scaled (log2e folded)
    const int h = o_base >> 5, c0 = o_base & 31;
    f16* base = qT + ((size_t)(b * HEADS + h) * NPIX) * DH + c0;
#pragma unroll
    for (int j = 0; j < 4; ++j) {
      f16x4 v = {(f16)(acc[0][j] * QK_SCALE), (f16)(acc[1][j] * QK_SCALE),
                 (f16)(acc[2][j] * QK_SCALE), (f16)(acc[3][j] * QK_SCALE)};
      *(f16x4*)(base + (size_t)(p_base + j) * DH) = v;
    }
  } else if (o_base < 2 * HID) {    // ---- K: kT[b][h][p][c]
    const int och = o_base - HID;
    const int h = och >> 5, c0 = och & 31;
    f16* base = kT + ((size_t)(b * HEADS + h) * NPIX) * DH + c0;
#pragma unroll
    for (int j = 0; j < 4; ++j) {
      f16x4 v = {(f16)acc[0][j], (f16)acc[1][j], (f16)acc[2][j], (f16)acc[3][j]};
      *(f16x4*)(base + (size_t)(p_base + j) * DH) = v;
    }
  } else {                          // ---- V: vO[b][h][c][p]
    const int och = o_base - 2 * HID;
    const int h = och >> 5, c0 = och & 31;
#pragma unroll
    for (int i = 0; i < 4; ++i) {
      f16x4 v = {(f16)acc[i][0], (f16)acc[i][1], (f16)acc[i][2], (f16)acc[i][3]};
      *(f16x4*)(vO + ((size_t)(b * HEADS + h) * DH + c0 + i) * NPIX + p_base) = v;
    }
  }
}

// ---------------- flash attention: barrier-free, LDS-free, f16 MFMA ----------------
// S^T = K Q^T so each lane's C-layout values share ONE attention row (i = lane&15).
// m/l are per-lane scalars; row reductions = local tree + shfl_xor(16,32).
// P (C-layout) -> PV B-operand layout via 16 shuffles + cndmask (quad-block permute).
// K double-buffered in registers; V loads issued at tile top, consumed post-softmax.
__global__ __launch_bounds__(256, 4) void attn_kernel(const f16* __restrict__ qT,
                                                      const f16* __restrict__ kT,
                                                      const f16* __restrict__ vO,
                                                      float* __restrict__ obuf) {
  const int i0 = blockIdx.x * 64;
  const int h = blockIdx.y;
  const int b = blockIdx.z;
  const int t = threadIdx.x;
  const int w = t >> 6;
  const int lane = t & 63;
  const int low4 = lane & 15;
  const int quad = lane >> 4;

  const size_t bh = (size_t)(b * HEADS + h);
  const f16* kp = kT + bh * NPIX * DH + (size_t)low4 * DH + quad * 8;
  const f16* vp = vO + bh * DH * NPIX + (size_t)low4 * NPIX + quad * 8;

  // Q fragment (B-operand layout): lane holds Q[i0+16w+low4][quad*8..+7]
  const f16x8 qf = *(const f16x8*)(qT + (bh * NPIX + i0 + w * 16 + low4) * DH + quad * 8);

  f32x4 ov0 = {0.f, 0.f, 0.f, 0.f}, ov1 = {0.f, 0.f, 0.f, 0.f};
  float m = -1e30f, l = 0.f;
  const f32x4 zero = {0.f, 0.f, 0.f, 0.f};
  const int srcA = low4 + 32 * (quad & 1);  // P-transform source lanes
  const int srcB = srcA + 16;
  const bool loq = quad < 2;

  union U8 { unsigned int u[4]; f16x8 v; };

  auto loadK = [&](f16x8* kb, int jt) {
#pragma unroll
    for (int tt = 0; tt < 4; ++tt)
      kb[tt] = *(const f16x8*)(kp + (size_t)(jt + 16 * tt) * DH);
  };

  auto tile = [&](const f16x8* kb, int jt) {
    // V fragments for this tile: issued early, needed only after softmax
    f16x8 vb00 = *(const f16x8*)(vp + jt);
    f16x8 vb01 = *(const f16x8*)(vp + jt + 32);
    f16x8 vb10 = *(const f16x8*)(vp + (size_t)16 * NPIX + jt);
    f16x8 vb11 = *(const f16x8*)(vp + (size_t)16 * NPIX + jt + 32);

    // S^T tile: D[j_local=16tt+4quad+r][i=low4], log2e pre-folded into Q
    f32x4 st[4];
#pragma unroll
    for (int tt = 0; tt < 4; ++tt)
      st[tt] = __builtin_amdgcn_mfma_f32_16x16x32_f16(kb[tt], qf, zero, 0, 0, 0);

    // row max: all 16 regs are row i=low4
    float mx = fmaxf(fmaxf(fmaxf(st[0][0], st[0][1]), fmaxf(st[0][2], st[0][3])),
                     fmaxf(fmaxf(st[1][0], st[1][1]), fmaxf(st[1][2], st[1][3])));
    mx = fmaxf(mx, fmaxf(fmaxf(fmaxf(st[2][0], st[2][1]), fmaxf(st[2][2], st[2][3])),
                         fmaxf(fmaxf(st[3][0], st[3][1]), fmaxf(st[3][2], st[3][3]))));
    mx = fmaxf(mx, __shfl_xor(mx, 16));
    mx = fmaxf(mx, __shfl_xor(mx, 32));
    const float mn = fmaxf(m, mx);
    const float al = __builtin_amdgcn_exp2f(m - mn);
    m = mn;

    float e[4][4];
    float sm = 0.f;
#pragma unroll
    for (int tt = 0; tt < 4; ++tt) {
#pragma unroll
      for (int r = 0; r < 4; ++r) {
        e[tt][r] = __builtin_amdgcn_exp2f(st[tt][r] - mn);
        sm += e[tt][r];
      }
    }
    sm += __shfl_xor(sm, 16);
    sm += __shfl_xor(sm, 32);
    l = l * al + sm;
#pragma unroll
    for (int r = 0; r < 4; ++r) { ov0[r] *= al; ov1[r] *= al; }

    // pack exp'd P to f16 pairs (j-order r0r1 / r2r3 per tt)
    unsigned int pk[4][2];
#pragma unroll
    for (int tt = 0; tt < 4; ++tt) {
      pk[tt][0] = __builtin_bit_cast(unsigned int,
                    __builtin_amdgcn_cvt_pkrtz(e[tt][0], e[tt][1]));
      pk[tt][1] = __builtin_bit_cast(unsigned int,
                    __builtin_amdgcn_cvt_pkrtz(e[tt][2], e[tt][3]));
    }

    // C-layout -> B-operand layout: lane(low4=i,quad) needs P[j=8quad+jj+32js][i]
    U8 bf[2];
#pragma unroll
    for (int js = 0; js < 2; ++js) {
      const int ttA = 2 * js, ttB = 2 * js + 1;
      int a0 = __shfl((int)pk[ttA][0], srcA), b0 = __shfl((int)pk[ttB][0], srcA);
      int a1 = __shfl((int)pk[ttA][1], srcA), b1 = __shfl((int)pk[ttB][1], srcA);
      int a2 = __shfl((int)pk[ttA][0], srcB), b2 = __shfl((int)pk[ttB][0], srcB);
      int a3 = __shfl((int)pk[ttA][1], srcB), b3 = __shfl((int)pk[ttB][1], srcB);
      bf[js].u[0] = loq ? (unsigned)a0 : (unsigned)b0;
      bf[js].u[1] = loq ? (unsigned)a1 : (unsigned)b1;
      bf[js].u[2] = loq ? (unsigned)a2 : (unsigned)b2;
      bf[js].u[3] = loq ? (unsigned)a3 : (unsigned)b3;
    }

    // O^T[c][i] += V P^T : A=V-frag (m=c), B=P-frag (n=i)
    ov0 = __builtin_amdgcn_mfma_f32_16x16x32_f16(vb00, bf[0].v, ov0, 0, 0, 0);
    ov0 = __builtin_amdgcn_mfma_f32_16x16x32_f16(vb01, bf[1].v, ov0, 0, 0, 0);
    ov1 = __builtin_amdgcn_mfma_f32_16x16x32_f16(vb10, bf[0].v, ov1, 0, 0, 0);
    ov1 = __builtin_amdgcn_mfma_f32_16x16x32_f16(vb11, bf[1].v, ov1, 0, 0, 0);
  };

  f16x8 kbA[4], kbB[4];
  loadK(kbA, 0);
  for (int jt = 0; jt < NPIX; jt += 128) {
    loadK(kbB, jt + 64);
    tile(kbA, jt);
    if (jt + 128 < NPIX) loadK(kbA, jt + 128);
    tile(kbB, jt + 64);
  }

  // epilogue: O^T in C-layout -> direct stores (16-lane/64B segments)
  const float inv = 1.f / l;
  float* ob = obuf + ((size_t)b * HID + h * DH) * NPIX + i0 + w * 16 + low4;
#pragma unroll
  for (int r = 0; r < 4; ++r) {
    ob[(size_t)(4 * quad + r) * NPIX]      = ov0[r] * inv;
    ob[(size_t)(16 + 4 * quad + r) * NPIX] = ov1[r] * inv;
  }
}

// ---------------- output projection GEMM + bias ----------------
__global__ __launch_bounds__(256) void out_gemm(const float* __restrict__ obuf,
                                                const float* __restrict__ wout,
                                                const float* __restrict__ bout,
                                                float* __restrict__ y) {
  const int b = blockIdx.z;
  const int o0 = blockIdx.y * 64;
  const int p0 = blockIdx.x * 64;
  const int t = threadIdx.x;
  __shared__ float As[16][64];
  __shared__ float Bs[16][68];
  const int to = t >> 4;
  const int tp = t & 15;
  const int lo = t >> 2;
  const int lkq = (t & 3) * 4;
  const int lk = t >> 4;
  const int lpq = (t & 15) * 4;
  float acc[4][4] = {};
  for (int k0 = 0; k0 < HID; k0 += 16) {
    float4 w4 = *(const float4*)(wout + (size_t)(o0 + lo) * HID + k0 + lkq);
    float4 v4 = *(const float4*)(obuf + ((size_t)b * HID + k0 + lk) * NPIX + p0 + lpq);
    As[lkq + 0][lo] = w4.x; As[lkq + 1][lo] = w4.y;
    As[lkq + 2][lo] = w4.z; As[lkq + 3][lo] = w4.w;
    *(float4*)&Bs[lk][lpq] = v4;
    __syncthreads();
#pragma unroll
    for (int k = 0; k < 16; ++k) {
      float4 a4 = *(const float4*)&As[k][to * 4];
      float4 b4 = *(const float4*)&Bs[k][tp * 4];
      acc[0][0] += a4.x * b4.x; acc[0][1] += a4.x * b4.y; acc[0][2] += a4.x * b4.z; acc[0][3] += a4.x * b4.w;
      acc[1][0] += a4.y * b4.x; acc[1][1] += a4.y * b4.y; acc[1][2] += a4.y * b4.z; acc[1][3] += a4.y * b4.w;
      acc[2][0] += a4.z * b4.x; acc[2][1] += a4.z * b4.y; acc[2][2] += a4.z * b4.z; acc[2][3] += a4.z * b4.w;
      acc[3][0] += a4.w * b4.x; acc[3][1] += a4.w * b4.y; acc[3][2] += a4.w * b4.z; acc[3][3] += a4.w * b4.w;
    }
    __syncthreads();
  }
#pragma unroll
  for (int i = 0; i < 4; ++i) {
    const float bias = bout[o0 + to * 4 + i];
    *(float4*)(y + ((size_t)b * CDIM + o0 + to * 4 + i) * NPIX + p0 + tp * 4) =
        make_float4(acc[i][0] + bias, acc[i][1] + bias, acc[i][2] + bias, acc[i][3] + bias);
  }
}

extern "C" void kernel_launch(void* const* d_in, const int* in_sizes, int n_in,
                              void* d_out, int out_size, void* d_ws, size_t ws_size,
                              hipStream_t stream) {
  const float* x     = (const float*)d_in[0];
  const float* gamma = (const float*)d_in[1];
  const float* beta  = (const float*)d_in[2];
  const float* wqkv  = (const float*)d_in[3];
  const float* wout  = (const float*)d_in[4];
  const float* bout  = (const float*)d_in[5];
  float* y = (float*)d_out;

  char* wsb = (char*)d_ws;
  float* part  = (float*)wsb;                       // 512 floats
  float* stats = part + 512;                        // 8 floats
  f16* qT = (f16*)(wsb + 4096);                     // 4MB
  f16* kT = qT + (size_t)BATCH * HEADS * NPIX * DH; // 4MB
  f16* vO = kT + (size_t)BATCH * HEADS * NPIX * DH; // 4MB
  float* obuf = (float*)(vO + (size_t)BATCH * HEADS * NPIX * DH);  // 8MB

  ln_reduce<<<dim3(256), 256, 0, stream>>>(x, part);
  ln_finalize<<<dim3(1), 256, 0, stream>>>(part, stats);
  qkv_gemm<<<dim3(64, 6, BATCH), 256, 0, stream>>>(x, gamma, beta, wqkv, stats, qT, kT, vO);
  attn_kernel<<<dim3(64, HEADS, BATCH), 256, 0, stream>>>(qT, kT, vO, obuf);
  out_gemm<<<dim3(64, 4, BATCH), 256, 0, stream>>>(obuf, wout, bout, y);
}